// Round 8
// baseline (267.666 us; speedup 1.0000x reference)
//
#include <hip/hip_runtime.h>

// Problem constants
#define BB 8
#define LL 1024
#define KNB 30
#define NUM_RBF 16
#define NPOS 16
#define MAXREL 32
#define EDGE_C 128
#define EDGE_IN 416   // NPOS + 25*NUM_RBF
#define NKK 26        // 416 / 16 K-steps for 32x32x16 MFMA
#define WTF_N (NKK * 4 * 64 * 8)   // 53248 fp8 BYTES (fragment-linear W)

__constant__ int PAIR_I_d[25] = {0,1,2,3,4,0,0,0,0,1,1,1,4,4,3,1,2,3,4,2,3,4,2,3,2};
__constant__ int PAIR_J_d[25] = {0,1,2,3,4,1,2,3,4,2,3,4,2,3,2,0,0,0,0,1,1,1,4,4,3};

typedef float floatx16 __attribute__((ext_vector_type(16)));

// -------- Kernel A: W_edge -> fragment-linear FP8 repack (runs first; stream
// order guarantees WtF is complete before the fused kernel's MFMA reads it). ----
__global__ __launch_bounds__(256) void wprep_kernel(const float* __restrict__ W_edge,
                                                    unsigned char* __restrict__ WtF) {
    // WtF[((kk*4+w)*64+l)*8+j] = fp8(W_edge[(kk*16+(l>>5)*8+j)*128 + w*32+(l&31)])
    int o = blockIdx.x * 256 + threadIdx.x;
    if (o < WTF_N) {
        int j = o & 7, l = (o >> 3) & 63, w = (o >> 9) & 3, kk = o >> 11;
        int k = (kk << 4) + ((l >> 5) << 3) + j;
        int n = (w << 5) + (l & 31);
        float wv = W_edge[k * EDGE_C + n];
        int pk = __builtin_amdgcn_cvt_pk_fp8_f32(wv, wv, 0, false);
        WtF[o] = (unsigned char)(pk & 0xFF);
    }
}

// -------- Kernel B: fused kNN + edge. One block per 4 rows (2048 blocks). ------
// v7 theory: r5's knn and edge dispatches are both latency-bound with every pipe
// <45% because all resident blocks march the same barrier phases in lockstep
// (and the kernel boundary stops knn/edge overlap entirely). Fusing makes blocks
// drift across the ~25-barrier sequence -> steady-state phase DIVERSITY per CU
// (block A's MFMA co-schedules with block B's exp2/LN, m114-style), kills the
// 8192-block launch, and keeps neighbor lists in LDS (480 B) instead of a
// global round-trip. Every phase body is byte-identical to proven r5.
__global__ __launch_bounds__(256) void fused_kernel(const float* __restrict__ X,
                                                    const float* __restrict__ mask,
                                                    const int* __restrict__ ridx,
                                                    const float* __restrict__ W_pos,
                                                    const float* __restrict__ b_pos,
                                                    const unsigned char* __restrict__ WtF,
                                                    const float* __restrict__ gamma,
                                                    const float* __restrict__ beta,
                                                    float* __restrict__ out_idx,
                                                    float* __restrict__ out_E) {
    int b = blockIdx.x >> 8;
    int i0 = (blockIdx.x & 255) * 4;
    int tid = threadIdx.x;
    int lane = tid & 63;
    int wv = tid >> 6;
    int l = lane;

    // LDS overlay (16896 B):
    //  knn phase : sCa f32[3072] @0 (12288B), sMask f32[1024] @12288 (4096B)
    //  persistent: nbrL int[4*30] @16384 (480B)
    //  edge phase: atoms @0 (1860B) / fA fp8 @0 (13312B) / Esh f32 @0 (16384B)
    //              dist f32[750] @13312 (3000B)
    __shared__ __align__(16) char smem[16896];
    float* sCa  = (float*)smem;
    float* sMask = (float*)(smem + 12288);
    int*   nbrL = (int*)(smem + 16384);
    unsigned char* fA = (unsigned char*)smem;
    float* Esh = (float*)smem;
    float* atoms = (float*)smem;
    float* dist = (float*)(smem + 13312);

    // ---------------- kNN phase (unchanged r5 logic; wave wv owns row i0+wv) ----
    for (int j = tid; j < LL; j += 256) {
        int base = (b * LL + j) * 12 + 3;     // Ca
        sCa[j * 3 + 0] = X[base + 0];
        sCa[j * 3 + 1] = X[base + 1];
        sCa[j * 3 + 2] = X[base + 2];
        sMask[j] = mask[b * LL + j];
    }
    __syncthreads();

    {
        int i = i0 + wv;
        int row = b * LL + i;
        float cax = sCa[i * 3 + 0], cay = sCa[i * 3 + 1], caz = sCa[i * 3 + 2];
        float mi = sMask[i];

        float Dv[16];
        float dmax = 0.0f;
#pragma unroll
        for (int c = 0; c < 16; ++c) {
            int j = lane + c * 64;
            float dx = cax - sCa[j * 3 + 0];
            float dy = cay - sCa[j * 3 + 1];
            float dz = caz - sCa[j * 3 + 2];
            float m2 = mi * sMask[j];
            float D = m2 * sqrtf(dx * dx + dy * dy + dz * dz + 1e-6f);
            Dv[c] = D;
            dmax = fmaxf(dmax, D);
        }
        for (int o = 32; o; o >>= 1) dmax = fmaxf(dmax, __shfl_down(dmax, o));
        dmax = __shfl(dmax, 0);

        // exact sortable key: Dadj_bits * 1024 + j  (< 2^41, exact in f64)
        double cand[16];
#pragma unroll
        for (int c = 0; c < 16; ++c) {
            int j = lane + c * 64;
            float m2 = mi * sMask[j];
            float Dadj = Dv[c] + (1.0f - m2) * dmax;
            unsigned int bits = __float_as_uint(Dadj);
            cand[c] = fma((double)bits, 1024.0, (double)j);
        }

        const double KILL = 9.0e15;
        float myj = 0.0f;
        for (int r = 0; r < KNB; ++r) {
            double a0 = fmin(cand[0], cand[1]);
            double a1 = fmin(cand[2], cand[3]);
            double a2 = fmin(cand[4], cand[5]);
            double a3 = fmin(cand[6], cand[7]);
            double a4 = fmin(cand[8], cand[9]);
            double a5 = fmin(cand[10], cand[11]);
            double a6 = fmin(cand[12], cand[13]);
            double a7 = fmin(cand[14], cand[15]);
            a0 = fmin(a0, a1); a2 = fmin(a2, a3); a4 = fmin(a4, a5); a6 = fmin(a6, a7);
            a0 = fmin(a0, a2); a4 = fmin(a4, a6);
            double m = fmin(a0, a4);
            for (int o = 32; o; o >>= 1) {
                double other = __shfl_down(m, o);
                m = fmin(m, other);
            }
            m = __shfl(m, 0);
            unsigned long long ku = (unsigned long long)m;   // exact
            int jw = __builtin_amdgcn_readfirstlane((int)(ku & 1023));
            bool own = (lane == (jw & 63));
            switch (jw >> 6) {
                case 0:  if (own) cand[0]  = KILL; break;
                case 1:  if (own) cand[1]  = KILL; break;
                case 2:  if (own) cand[2]  = KILL; break;
                case 3:  if (own) cand[3]  = KILL; break;
                case 4:  if (own) cand[4]  = KILL; break;
                case 5:  if (own) cand[5]  = KILL; break;
                case 6:  if (own) cand[6]  = KILL; break;
                case 7:  if (own) cand[7]  = KILL; break;
                case 8:  if (own) cand[8]  = KILL; break;
                case 9:  if (own) cand[9]  = KILL; break;
                case 10: if (own) cand[10] = KILL; break;
                case 11: if (own) cand[11] = KILL; break;
                case 12: if (own) cand[12] = KILL; break;
                case 13: if (own) cand[13] = KILL; break;
                case 14: if (own) cand[14] = KILL; break;
                case 15: if (own) cand[15] = KILL; break;
            }
            if (lane == r) myj = (float)jw;
        }
        if (lane < KNB) {
            out_idx[(size_t)row * KNB + lane] = myj;     // E_idx output
            nbrL[wv * KNB + lane] = (int)myj;            // local copy for edge
        }
    }
    __syncthreads();   // nbrL complete; all sCa/sMask reads done (atoms overlays)

    // Constants across the 4 edge rows
    const long* Bp = (const long*)WtF + wv * 64 + l;     // + kk*256
    int cg = tid & 31;
    int ky = tid >> 5;
    int c0 = cg * 4;
    float gam0 = gamma[c0 + 0], gam1 = gamma[c0 + 1];
    float gam2 = gamma[c0 + 2], gam3 = gamma[c0 + 3];
    float bet0 = beta[c0 + 0], bet1 = beta[c0 + 1];
    float bet2 = beta[c0 + 2], bet3 = beta[c0 + 3];

    // ---------------- edge phase x4 (unchanged r5 pipeline per row) -------------
    for (int q = 0; q < 4; ++q) {
        int i = i0 + q;
        int row = b * LL + i;

        // step 1: atoms for residue i and its 30 neighbors (from nbrL)
        if (tid < 31) {
            int r = (tid == 0) ? i : nbrL[q * KNB + (tid - 1)];
            int base = (b * LL + r) * 12;
            float Nx = X[base + 0], Ny = X[base + 1], Nz = X[base + 2];
            float Cax = X[base + 3], Cay = X[base + 4], Caz = X[base + 5];
            float Cx = X[base + 6], Cy = X[base + 7], Cz = X[base + 8];
            float Ox = X[base + 9], Oy = X[base + 10], Oz = X[base + 11];
            float bx = Cax - Nx, by = Cay - Ny, bz = Caz - Nz;
            float cx = Cx - Cax, cy = Cy - Cay, cz = Cz - Caz;
            float ax = by * cz - bz * cy;
            float ay = bz * cx - bx * cz;
            float az = bx * cy - by * cx;
            float Cbx = -0.58273431f * ax + 0.56802827f * bx - 0.54067466f * cx + Cax;
            float Cby = -0.58273431f * ay + 0.56802827f * by - 0.54067466f * cy + Cay;
            float Cbz = -0.58273431f * az + 0.56802827f * bz - 0.54067466f * cz + Caz;
            float* A = &atoms[tid * 15];
            A[0] = Cax; A[1] = Cay; A[2] = Caz;
            A[3] = Nx;  A[4] = Ny;  A[5] = Nz;
            A[6] = Cx;  A[7] = Cy;  A[8] = Cz;
            A[9] = Ox;  A[10] = Oy; A[11] = Oz;
            A[12] = Cbx; A[13] = Cby; A[14] = Cbz;
        }
        __syncthreads();

        // step 2: 30*25 atom-pair distances
        for (int idx = tid; idx < KNB * 25; idx += 256) {
            int k = idx / 25;
            int p = idx - k * 25;
            const float* Ai = &atoms[PAIR_I_d[p] * 3];
            const float* Aj = &atoms[(1 + k) * 15 + PAIR_J_d[p] * 3];
            float dx = Ai[0] - Aj[0], dy = Ai[1] - Aj[1], dz = Ai[2] - Aj[2];
            dist[idx] = __builtin_amdgcn_sqrtf(dx * dx + dy * dy + dz * dz + 1e-6f);
        }
        __syncthreads();

        // step 3: build fp8 A-fragments; telescoped RBF (center anchor, xc<=12
        // clamp = NaN guard; chunks with xc>7.3 are exactly 0 in fp8 either way)
        {
            int m = tid & 31;
            int kgb = tid >> 5;
            float cbase = (kgb & 1) ? 14.4f : 5.8666668f;
            const float SQL2E = 1.2011224f;   // sqrt(log2 e)
            const float C1 = 3.0777494f;      // 2h * log2 e
            const float C0 = 1.6414664f;      // h^2 * log2 e
            const float DK = 0.1027397f;      // exp(-2 h^2)
#pragma unroll
            for (int r = 0; r < 7; ++r) {
                int kg = kgb + 8 * r;
                if (kg < 52) {
                    int lo, hi;
                    if (m >= KNB) {
                        lo = 0; hi = 0;
                    } else if (kg < 2) {
                        int jn = nbrL[q * KNB + m];
                        int off = ridx[row] - ridx[b * LL + jn] + MAXREL;
                        off = off < 0 ? 0 : (off > 2 * MAXREL ? 2 * MAXREL : off);
                        const float4* wp = (const float4*)&W_pos[off * NPOS + kg * 8];
                        const float4* bp = (const float4*)&b_pos[kg * 8];
                        float4 w0 = wp[0], w1 = wp[1];
                        float4 p0 = bp[0], p1 = bp[1];
                        lo = __builtin_amdgcn_cvt_pk_fp8_f32(w0.x + p0.x, w0.y + p0.y, 0, false);
                        lo = __builtin_amdgcn_cvt_pk_fp8_f32(w0.z + p0.z, w0.w + p0.w, lo, true);
                        hi = __builtin_amdgcn_cvt_pk_fp8_f32(w1.x + p1.x, w1.y + p1.y, 0, false);
                        hi = __builtin_amdgcn_cvt_pk_fp8_f32(w1.z + p1.z, w1.w + p1.w, hi, true);
                    } else {
                        int p = (kg - 2) >> 1;
                        float d = dist[m * 25 + p];
                        float xc = fminf(fmaf(0.8f, d, -cbase), 12.0f);
                        float xs = xc * SQL2E;
                        float r4 = __builtin_amdgcn_exp2f(-xs * xs);
                        float fw = __builtin_amdgcn_exp2f(fmaf(C1, xc, -C0));
                        float bw = __builtin_amdgcn_exp2f(fmaf(-C1, xc, -C0));
                        float r5 = r4 * fw; fw *= DK;
                        float r6 = r5 * fw; fw *= DK;
                        float r7 = r6 * fw;
                        float r3 = r4 * bw; bw *= DK;
                        float r2 = r3 * bw; bw *= DK;
                        float r1 = r2 * bw; bw *= DK;
                        float r0 = r1 * bw;
                        lo = __builtin_amdgcn_cvt_pk_fp8_f32(r0, r1, 0, false);
                        lo = __builtin_amdgcn_cvt_pk_fp8_f32(r2, r3, lo, true);
                        hi = __builtin_amdgcn_cvt_pk_fp8_f32(r4, r5, 0, false);
                        hi = __builtin_amdgcn_cvt_pk_fp8_f32(r6, r7, hi, true);
                    }
                    int pos = ((kg >> 1) * 64 + m + 32 * (kg & 1)) * 8;
                    long v = ((long)(unsigned int)hi << 32) | (unsigned int)lo;
                    *(long*)(fA + pos) = v;
                }
            }
        }
        __syncthreads();

        // step 4: FP8 MFMA K-loop (B loads in-loop, L2-hot — proven r5 pattern)
        floatx16 acc;
#pragma unroll
        for (int r = 0; r < 16; ++r) acc[r] = 0.0f;
        const long* Ap = (const long*)fA + l;
#pragma unroll 4
        for (int kk = 0; kk < NKK; ++kk) {
            long a = Ap[kk * 64];
            long bfr = Bp[kk * 256];
            acc = __builtin_amdgcn_mfma_f32_32x32x16_fp8_fp8(a, bfr, acc, 0, 0, 0);
        }
        __syncthreads();   // all reads of fA done before Esh overlay

        // step 5: spill C to LDS (col=l&31, row=(r&3)+8*(r>>2)+4*(l>>5))
#pragma unroll
        for (int r = 0; r < 16; ++r) {
            int rr = (r & 3) + 8 * (r >> 2) + 4 * (l >> 5);
            Esh[rr * EDGE_C + wv * 32 + (l & 31)] = acc[r];
        }
        __syncthreads();

        // step 6: one-pass LayerNorm (interleaved s/q butterflies, v_rsq)
#pragma unroll
        for (int r2 = 0; r2 < 4; ++r2) {
            int e = ky + 8 * r2;
            float4 v = *(const float4*)&Esh[e * EDGE_C + c0];
            float s = (v.x + v.y) + (v.z + v.w);
            float qq = fmaf(v.x, v.x, fmaf(v.y, v.y, fmaf(v.z, v.z, v.w * v.w)));
#pragma unroll
            for (int o = 16; o; o >>= 1) {
                s += __shfl_xor(s, o);
                qq += __shfl_xor(qq, o);
            }
            float mean = s * 0.0078125f;
            float var = fmaf(-mean, mean, qq * 0.0078125f);
            float inv = __builtin_amdgcn_rsqf(var + 1e-5f);
            if (e < KNB) {
                float ig0 = inv * gam0, ig1 = inv * gam1;
                float ig2 = inv * gam2, ig3 = inv * gam3;
                float4 o4;
                o4.x = fmaf(v.x, ig0, fmaf(-mean, ig0, bet0));
                o4.y = fmaf(v.y, ig1, fmaf(-mean, ig1, bet1));
                o4.z = fmaf(v.z, ig2, fmaf(-mean, ig2, bet2));
                o4.w = fmaf(v.w, ig3, fmaf(-mean, ig3, bet3));
                *(float4*)(out_E + ((size_t)(row * KNB + e)) * EDGE_C + c0) = o4;
            }
        }
        __syncthreads();   // Esh reads done before next row's atoms overwrite
    }
}

extern "C" void kernel_launch(void* const* d_in, const int* in_sizes, int n_in,
                              void* d_out, int out_size, void* d_ws, size_t ws_size,
                              hipStream_t stream) {
    const float* X      = (const float*)d_in[0];
    const float* mask   = (const float*)d_in[1];
    const int*   ridx   = (const int*)d_in[2];
    const float* W_pos  = (const float*)d_in[6];
    const float* b_pos  = (const float*)d_in[7];
    const float* W_edge = (const float*)d_in[8];
    const float* gamma  = (const float*)d_in[9];
    const float* beta   = (const float*)d_in[10];

    float* out_E   = (float*)d_out;
    float* out_idx = out_E + (size_t)BB * LL * KNB * EDGE_C;   // E_idx stored as floats
    unsigned char* WtF = (unsigned char*)d_ws;                 // 53 KB fragment-linear fp8 W

    wprep_kernel<<<(WTF_N + 255) / 256, 256, 0, stream>>>(W_edge, WtF);
    fused_kernel<<<BB * LL / 4, 256, 0, stream>>>(X, mask, ridx, W_pos, b_pos, WtF,
                                                  gamma, beta, out_idx, out_E);
}

// Round 9
// 242.433 us; speedup vs baseline: 1.1041x; 1.1041x over previous
//
#include <hip/hip_runtime.h>

// Problem constants
#define BB 8
#define LL 1024
#define KNB 30
#define NUM_RBF 16
#define NPOS 16
#define MAXREL 32
#define EDGE_C 128
#define EDGE_IN 416   // NPOS + 25*NUM_RBF
#define NKK 26        // 416 / 16 K-steps for 32x32x16 MFMA
#define WTF_N (NKK * 4 * 64 * 8)   // 53248 fp8 BYTES (fragment-linear W)

__constant__ int PAIR_I_d[25] = {0,1,2,3,4,0,0,0,0,1,1,1,4,4,3,1,2,3,4,2,3,4,2,3,2};
__constant__ int PAIR_J_d[25] = {0,1,2,3,4,1,2,3,4,2,3,4,2,3,2,0,0,0,0,1,1,1,4,4,3};

typedef float floatx16 __attribute__((ext_vector_type(16)));

// -------- Kernel 1: kNN (4 rows per 256-thread block; one wave per row) --------
// Byte-identical to r5 (proven). Blocks >= 2048 repack W_edge into
// fragment-linear FP8 (folded wprep). Exact f64 sortable keys + IEEE sqrtf.
__global__ __launch_bounds__(256) void knn_kernel(const float* __restrict__ X,
                                                  const float* __restrict__ mask,
                                                  float* __restrict__ out_idx,
                                                  const float* __restrict__ W_edge,
                                                  unsigned char* __restrict__ WtF) {
    if (blockIdx.x >= 2048) {
        // WtF[((kk*4+w)*64+l)*8+j] = fp8(W_edge[(kk*16+(l>>5)*8+j)*128 + w*32+(l&31)])
        int o = (blockIdx.x - 2048) * 256 + threadIdx.x;
        if (o < WTF_N) {
            int j = o & 7, l = (o >> 3) & 63, w = (o >> 9) & 3, kk = o >> 11;
            int k = (kk << 4) + ((l >> 5) << 3) + j;
            int n = (w << 5) + (l & 31);
            float wv = W_edge[k * EDGE_C + n];
            int pk = __builtin_amdgcn_cvt_pk_fp8_f32(wv, wv, 0, false);
            WtF[o] = (unsigned char)(pk & 0xFF);
        }
        return;
    }

    int b = blockIdx.x >> 8;
    int i0 = (blockIdx.x & 255) * 4;
    int tid = threadIdx.x;
    int lane = tid & 63;
    int wv = tid >> 6;

    __shared__ float sCa[LL * 3];
    __shared__ float sMask[LL];

    for (int j = tid; j < LL; j += 256) {
        int base = (b * LL + j) * 12 + 3;     // Ca
        sCa[j * 3 + 0] = X[base + 0];
        sCa[j * 3 + 1] = X[base + 1];
        sCa[j * 3 + 2] = X[base + 2];
        sMask[j] = mask[b * LL + j];
    }
    __syncthreads();

    int i = i0 + wv;
    int row = b * LL + i;
    float cax = sCa[i * 3 + 0], cay = sCa[i * 3 + 1], caz = sCa[i * 3 + 2];
    float mi = sMask[i];

    float Dv[16];
    float dmax = 0.0f;
#pragma unroll
    for (int c = 0; c < 16; ++c) {
        int j = lane + c * 64;
        float dx = cax - sCa[j * 3 + 0];
        float dy = cay - sCa[j * 3 + 1];
        float dz = caz - sCa[j * 3 + 2];
        float m2 = mi * sMask[j];
        float D = m2 * sqrtf(dx * dx + dy * dy + dz * dz + 1e-6f);
        Dv[c] = D;
        dmax = fmaxf(dmax, D);
    }
    for (int o = 32; o; o >>= 1) dmax = fmaxf(dmax, __shfl_down(dmax, o));
    dmax = __shfl(dmax, 0);

    // exact sortable key: Dadj_bits * 1024 + j  (< 2^41, exact in f64)
    double cand[16];
#pragma unroll
    for (int c = 0; c < 16; ++c) {
        int j = lane + c * 64;
        float m2 = mi * sMask[j];
        float Dadj = Dv[c] + (1.0f - m2) * dmax;
        unsigned int bits = __float_as_uint(Dadj);
        cand[c] = fma((double)bits, 1024.0, (double)j);
    }

    const double KILL = 9.0e15;
    float myj = 0.0f;
    for (int r = 0; r < KNB; ++r) {
        double a0 = fmin(cand[0], cand[1]);
        double a1 = fmin(cand[2], cand[3]);
        double a2 = fmin(cand[4], cand[5]);
        double a3 = fmin(cand[6], cand[7]);
        double a4 = fmin(cand[8], cand[9]);
        double a5 = fmin(cand[10], cand[11]);
        double a6 = fmin(cand[12], cand[13]);
        double a7 = fmin(cand[14], cand[15]);
        a0 = fmin(a0, a1); a2 = fmin(a2, a3); a4 = fmin(a4, a5); a6 = fmin(a6, a7);
        a0 = fmin(a0, a2); a4 = fmin(a4, a6);
        double m = fmin(a0, a4);
        for (int o = 32; o; o >>= 1) {
            double other = __shfl_down(m, o);
            m = fmin(m, other);
        }
        m = __shfl(m, 0);
        unsigned long long ku = (unsigned long long)m;   // exact
        int jw = __builtin_amdgcn_readfirstlane((int)(ku & 1023));
        bool own = (lane == (jw & 63));
        switch (jw >> 6) {
            case 0:  if (own) cand[0]  = KILL; break;
            case 1:  if (own) cand[1]  = KILL; break;
            case 2:  if (own) cand[2]  = KILL; break;
            case 3:  if (own) cand[3]  = KILL; break;
            case 4:  if (own) cand[4]  = KILL; break;
            case 5:  if (own) cand[5]  = KILL; break;
            case 6:  if (own) cand[6]  = KILL; break;
            case 7:  if (own) cand[7]  = KILL; break;
            case 8:  if (own) cand[8]  = KILL; break;
            case 9:  if (own) cand[9]  = KILL; break;
            case 10: if (own) cand[10] = KILL; break;
            case 11: if (own) cand[11] = KILL; break;
            case 12: if (own) cand[12] = KILL; break;
            case 13: if (own) cand[13] = KILL; break;
            case 14: if (own) cand[14] = KILL; break;
            case 15: if (own) cand[15] = KILL; break;
        }
        if (lane == r) myj = (float)jw;
    }
    if (lane < KNB) out_idx[(size_t)row * KNB + lane] = myj;
}

// -------- Kernel 2: edge, TWO rows per block (512 threads, 8 waves) ------------
// v9: r5's per-wave schedule kept byte-equivalent; waves split M: wave wv ->
// (wr=wv>>2 row-tile, wc=wv&3 col-slice). Per-block serial chain LENGTH is
// unchanged (each phase 2x work on 2x threads); block generations per CU halve
// (32 -> 16) at IDENTICAL wave residency (LDS 32768 -> 4 blk/CU x 8 waves = 32,
// vs r5 8 x 4 = 32). Attacks the latency-bound chain count without r4's
// (less MFMA/barrier) or r8's (single-generation lockstep) failure modes.
__global__ __launch_bounds__(512) void edge_kernel(const float* __restrict__ X,
                                                   const int* __restrict__ ridx,
                                                   const float* __restrict__ W_pos,
                                                   const float* __restrict__ b_pos,
                                                   const unsigned char* __restrict__ WtF,
                                                   const float* __restrict__ gamma,
                                                   const float* __restrict__ beta,
                                                   const float* __restrict__ out_idx,
                                                   float* __restrict__ out_E) {
    int b = blockIdx.x >> 9;
    int i0 = (blockIdx.x & 511) * 2;     // two output rows: i0, i0+1
    int tid = threadIdx.x;
    int lane = tid & 63;

    // LDS overlay (32768 B):
    //  dist  f32[1500]        @0      [0, 6000)         live steps 2-3
    //  atoms f32[2*31*15]     @6016   [6016, 9736)      live steps 1-2 (dead pre-fA)
    //  fA    fp8[2*13312]     @6144   [6144, 32768)     live steps 3-4
    //  Esh   f32[64*128]      @0      [0, 32768)        after step-4 barrier
    __shared__ __align__(16) char smem[32768];
    float* dist  = (float*)smem;
    float* atoms = (float*)(smem + 6016);
    unsigned char* fA = (unsigned char*)(smem + 6144);
    float* Esh = (float*)smem;

    // step 1: atoms for both rows (wave 0: lanes 0-61 cover 2 x 31 residues)
    if (tid < 62) {
        int q = tid >= 31 ? 1 : 0;
        int tt = tid - 31 * q;
        int rowq = b * LL + i0 + q;
        int r = (tt == 0) ? (i0 + q) : (int)out_idx[(size_t)rowq * KNB + (tt - 1)];
        int base = (b * LL + r) * 12;
        float Nx = X[base + 0], Ny = X[base + 1], Nz = X[base + 2];
        float Cax = X[base + 3], Cay = X[base + 4], Caz = X[base + 5];
        float Cx = X[base + 6], Cy = X[base + 7], Cz = X[base + 8];
        float Ox = X[base + 9], Oy = X[base + 10], Oz = X[base + 11];
        float bx = Cax - Nx, by = Cay - Ny, bz = Caz - Nz;
        float cx = Cx - Cax, cy = Cy - Cay, cz = Cz - Caz;
        float ax = by * cz - bz * cy;
        float ay = bz * cx - bx * cz;
        float az = bx * cy - by * cx;
        float Cbx = -0.58273431f * ax + 0.56802827f * bx - 0.54067466f * cx + Cax;
        float Cby = -0.58273431f * ay + 0.56802827f * by - 0.54067466f * cy + Cay;
        float Cbz = -0.58273431f * az + 0.56802827f * bz - 0.54067466f * cz + Caz;
        float* A = &atoms[(q * 31 + tt) * 15];
        A[0] = Cax; A[1] = Cay; A[2] = Caz;
        A[3] = Nx;  A[4] = Ny;  A[5] = Nz;
        A[6] = Cx;  A[7] = Cy;  A[8] = Cz;
        A[9] = Ox;  A[10] = Oy; A[11] = Oz;
        A[12] = Cbx; A[13] = Cby; A[14] = Cbz;
    }
    __syncthreads();

    // step 2: 2 x 750 atom-pair distances
    for (int idx = tid; idx < 2 * KNB * 25; idx += 512) {
        int t = idx >= 750 ? 1 : 0;
        int rem = idx - 750 * t;
        int k = rem / 25;
        int p = rem - k * 25;
        const float* Ai = &atoms[(t * 31) * 15 + PAIR_I_d[p] * 3];
        const float* Aj = &atoms[(t * 31 + 1 + k) * 15 + PAIR_J_d[p] * 3];
        float dx = Ai[0] - Aj[0], dy = Ai[1] - Aj[1], dz = Ai[2] - Aj[2];
        dist[idx] = __builtin_amdgcn_sqrtf(dx * dx + dy * dy + dz * dz + 1e-6f);
    }
    __syncthreads();

    // step 3: build fp8 A-fragments for both row-tiles.
    // tile t, element (mm,k): fA[t*13312 + ((k>>4)*64 + mm + 32*((k>>3)&1))*8 + (k&7)]
    // Telescoped RBF, center anchor, xc<=12 clamp (NaN guard; chunks with
    // xc>7.3 are exactly 0 in fp8 either way -> semantics-preserving).
    {
        int m = tid & 63;
        int t = m >> 5;
        int mm = m & 31;
        int kgb = tid >> 6;          // 0..7; kg parity == kgb parity
        float cbase = (kgb & 1) ? 14.4f : 5.8666668f;   // 1.6 + 4h (+ 8h odd chunks)
        const float SQL2E = 1.2011224f;   // sqrt(log2 e)
        const float C1 = 3.0777494f;      // 2h * log2 e
        const float C0 = 1.6414664f;      // h^2 * log2 e
        const float DK = 0.1027397f;      // exp(-2 h^2)
        int rowq = b * LL + i0 + t;
#pragma unroll
        for (int r = 0; r < 7; ++r) {
            int kg = kgb + 8 * r;
            if (kg < 52) {
                int lo, hi;
                if (mm >= KNB) {
                    lo = 0; hi = 0;
                } else if (kg < 2) {
                    // positional features; dclip inline (out_idx/ridx L2-hot)
                    int jn = (int)out_idx[(size_t)rowq * KNB + mm];
                    int off = ridx[rowq] - ridx[b * LL + jn] + MAXREL;
                    off = off < 0 ? 0 : (off > 2 * MAXREL ? 2 * MAXREL : off);
                    const float4* wp = (const float4*)&W_pos[off * NPOS + kg * 8];
                    const float4* bp = (const float4*)&b_pos[kg * 8];
                    float4 w0 = wp[0], w1 = wp[1];
                    float4 p0 = bp[0], p1 = bp[1];
                    lo = __builtin_amdgcn_cvt_pk_fp8_f32(w0.x + p0.x, w0.y + p0.y, 0, false);
                    lo = __builtin_amdgcn_cvt_pk_fp8_f32(w0.z + p0.z, w0.w + p0.w, lo, true);
                    hi = __builtin_amdgcn_cvt_pk_fp8_f32(w1.x + p1.x, w1.y + p1.y, 0, false);
                    hi = __builtin_amdgcn_cvt_pk_fp8_f32(w1.z + p1.z, w1.w + p1.w, hi, true);
                } else {
                    int p = (kg - 2) >> 1;
                    float d = dist[t * 750 + mm * 25 + p];
                    float xc = fminf(fmaf(0.8f, d, -cbase), 12.0f);
                    float xs = xc * SQL2E;
                    float r4 = __builtin_amdgcn_exp2f(-xs * xs);
                    float fw = __builtin_amdgcn_exp2f(fmaf(C1, xc, -C0));
                    float bw = __builtin_amdgcn_exp2f(fmaf(-C1, xc, -C0));
                    float r5 = r4 * fw; fw *= DK;
                    float r6 = r5 * fw; fw *= DK;
                    float r7 = r6 * fw;
                    float r3 = r4 * bw; bw *= DK;
                    float r2 = r3 * bw; bw *= DK;
                    float r1 = r2 * bw; bw *= DK;
                    float r0 = r1 * bw;
                    lo = __builtin_amdgcn_cvt_pk_fp8_f32(r0, r1, 0, false);
                    lo = __builtin_amdgcn_cvt_pk_fp8_f32(r2, r3, lo, true);
                    hi = __builtin_amdgcn_cvt_pk_fp8_f32(r4, r5, 0, false);
                    hi = __builtin_amdgcn_cvt_pk_fp8_f32(r6, r7, hi, true);
                }
                int pos = t * 13312 + ((kg >> 1) * 64 + mm + 32 * (kg & 1)) * 8;
                long v = ((long)(unsigned int)hi << 32) | (unsigned int)lo;
                *(long*)(fA + pos) = v;
            }
        }
    }
    __syncthreads();

    // step 4: FP8 MFMA K-loop. wave wv -> row-tile wr, col-slice wc.
    int wv = tid >> 6;
    int wr = wv >> 2;
    int wc = wv & 3;
    floatx16 acc;
#pragma unroll
    for (int r = 0; r < 16; ++r) acc[r] = 0.0f;

    const long* Ap = (const long*)(fA + wr * 13312) + lane;     // + kk*64
    const long* Bp = (const long*)WtF + wc * 64 + lane;         // + kk*256
#pragma unroll 4
    for (int kk = 0; kk < NKK; ++kk) {
        long a = Ap[kk * 64];
        long bfr = Bp[kk * 256];
        acc = __builtin_amdgcn_mfma_f32_32x32x16_fp8_fp8(a, bfr, acc, 0, 0, 0);
    }
    __syncthreads();   // fA + dist dead before Esh overlay

    // step 5: spill C to LDS (tile wr rows 0..31 -> Esh rows wr*32+rr)
#pragma unroll
    for (int r = 0; r < 16; ++r) {
        int rr = (r & 3) + 8 * (r >> 2) + 4 * (lane >> 5);
        Esh[(wr * 32 + rr) * EDGE_C + wc * 32 + (lane & 31)] = acc[r];
    }
    __syncthreads();

    // step 6: one-pass LayerNorm over 64 Esh rows (rows 0-29 -> i0, 32-61 -> i0+1)
    int cg = tid & 31;
    int ky = tid >> 5;            // 0..15
    int c0 = cg * 4;
    float gam0 = gamma[c0 + 0], gam1 = gamma[c0 + 1];
    float gam2 = gamma[c0 + 2], gam3 = gamma[c0 + 3];
    float bet0 = beta[c0 + 0], bet1 = beta[c0 + 1];
    float bet2 = beta[c0 + 2], bet3 = beta[c0 + 3];

#pragma unroll
    for (int r2 = 0; r2 < 4; ++r2) {
        int e = ky + 16 * r2;     // 0..63
        int t = e >> 5;
        int el = e & 31;
        float4 v = *(const float4*)&Esh[e * EDGE_C + c0];
        float s = (v.x + v.y) + (v.z + v.w);
        float qq = fmaf(v.x, v.x, fmaf(v.y, v.y, fmaf(v.z, v.z, v.w * v.w)));
#pragma unroll
        for (int o = 16; o; o >>= 1) {
            s += __shfl_xor(s, o);
            qq += __shfl_xor(qq, o);
        }
        float mean = s * 0.0078125f;
        float var = fmaf(-mean, mean, qq * 0.0078125f);
        float inv = __builtin_amdgcn_rsqf(var + 1e-5f);
        if (el < KNB) {
            float ig0 = inv * gam0, ig1 = inv * gam1;
            float ig2 = inv * gam2, ig3 = inv * gam3;
            float4 o4;
            o4.x = fmaf(v.x, ig0, fmaf(-mean, ig0, bet0));
            o4.y = fmaf(v.y, ig1, fmaf(-mean, ig1, bet1));
            o4.z = fmaf(v.z, ig2, fmaf(-mean, ig2, bet2));
            o4.w = fmaf(v.w, ig3, fmaf(-mean, ig3, bet3));
            size_t orow = (size_t)(b * LL + i0 + t) * KNB + el;
            *(float4*)(out_E + orow * EDGE_C + c0) = o4;
        }
    }
}

extern "C" void kernel_launch(void* const* d_in, const int* in_sizes, int n_in,
                              void* d_out, int out_size, void* d_ws, size_t ws_size,
                              hipStream_t stream) {
    const float* X      = (const float*)d_in[0];
    const float* mask   = (const float*)d_in[1];
    const int*   ridx   = (const int*)d_in[2];
    const float* W_pos  = (const float*)d_in[6];
    const float* b_pos  = (const float*)d_in[7];
    const float* W_edge = (const float*)d_in[8];
    const float* gamma  = (const float*)d_in[9];
    const float* beta   = (const float*)d_in[10];

    float* out_E   = (float*)d_out;
    float* out_idx = out_E + (size_t)BB * LL * KNB * EDGE_C;   // E_idx stored as floats
    unsigned char* WtF = (unsigned char*)d_ws;                 // 53 KB fragment-linear fp8 W

    int knn_grid = 2048 + (WTF_N + 255) / 256;   // kNN blocks + folded W-prep blocks
    knn_kernel<<<knn_grid, 256, 0, stream>>>(X, mask, out_idx, W_edge, WtF);
    edge_kernel<<<BB * LL / 2, 512, 0, stream>>>(X, ridx, W_pos, b_pos, WtF,
                                                 gamma, beta, out_idx, out_E);
}

// Round 10
// 240.055 us; speedup vs baseline: 1.1150x; 1.0099x over previous
//
#include <hip/hip_runtime.h>

// Problem constants
#define BB 8
#define LL 1024
#define KNB 30
#define NUM_RBF 16
#define NPOS 16
#define MAXREL 32
#define EDGE_C 128
#define EDGE_IN 416   // NPOS + 25*NUM_RBF
#define NKK 26        // 416 / 16 K-steps for 32x32x16 MFMA
#define WTF_N (NKK * 4 * 64 * 8)   // 53248 fp8 BYTES (fragment-linear W)

__constant__ int PAIR_I_d[25] = {0,1,2,3,4,0,0,0,0,1,1,1,4,4,3,1,2,3,4,2,3,4,2,3,2};
__constant__ int PAIR_J_d[25] = {0,1,2,3,4,1,2,3,4,2,3,4,2,3,2,0,0,0,0,1,1,1,4,4,3};

typedef float floatx16 __attribute__((ext_vector_type(16)));

// -------- Kernel 1: kNN (4 rows per 256-thread block; one wave per row) --------
// Blocks >= 2048 instead repack W_edge into fragment-linear FP8 (folded wprep).
// UNCHANGED selection path: exact f64 sortable keys + IEEE sqrtf (index output
// must match ref ordering bit-exactly; approx sqrt could reorder near-ties).
__global__ __launch_bounds__(256) void knn_kernel(const float* __restrict__ X,
                                                  const float* __restrict__ mask,
                                                  float* __restrict__ out_idx,
                                                  const float* __restrict__ W_edge,
                                                  unsigned char* __restrict__ WtF) {
    if (blockIdx.x >= 2048) {
        // WtF[((kk*4+w)*64+l)*8+j] = fp8(W_edge[(kk*16+(l>>5)*8+j)*128 + w*32+(l&31)])
        int o = (blockIdx.x - 2048) * 256 + threadIdx.x;
        if (o < WTF_N) {
            int j = o & 7, l = (o >> 3) & 63, w = (o >> 9) & 3, kk = o >> 11;
            int k = (kk << 4) + ((l >> 5) << 3) + j;
            int n = (w << 5) + (l & 31);
            float wv = W_edge[k * EDGE_C + n];
            int pk = __builtin_amdgcn_cvt_pk_fp8_f32(wv, wv, 0, false);
            WtF[o] = (unsigned char)(pk & 0xFF);
        }
        return;
    }

    int b = blockIdx.x >> 8;
    int i0 = (blockIdx.x & 255) * 4;
    int tid = threadIdx.x;
    int lane = tid & 63;
    int wv = tid >> 6;

    __shared__ float sCa[LL * 3];
    __shared__ float sMask[LL];

    for (int j = tid; j < LL; j += 256) {
        int base = (b * LL + j) * 12 + 3;     // Ca
        sCa[j * 3 + 0] = X[base + 0];
        sCa[j * 3 + 1] = X[base + 1];
        sCa[j * 3 + 2] = X[base + 2];
        sMask[j] = mask[b * LL + j];
    }
    __syncthreads();

    int i = i0 + wv;
    int row = b * LL + i;
    float cax = sCa[i * 3 + 0], cay = sCa[i * 3 + 1], caz = sCa[i * 3 + 2];
    float mi = sMask[i];

    float Dv[16];
    float dmax = 0.0f;
#pragma unroll
    for (int c = 0; c < 16; ++c) {
        int j = lane + c * 64;
        float dx = cax - sCa[j * 3 + 0];
        float dy = cay - sCa[j * 3 + 1];
        float dz = caz - sCa[j * 3 + 2];
        float m2 = mi * sMask[j];
        float D = m2 * sqrtf(dx * dx + dy * dy + dz * dz + 1e-6f);
        Dv[c] = D;
        dmax = fmaxf(dmax, D);
    }
    for (int o = 32; o; o >>= 1) dmax = fmaxf(dmax, __shfl_down(dmax, o));
    dmax = __shfl(dmax, 0);

    // exact sortable key: Dadj_bits * 1024 + j  (< 2^41, exact in f64)
    double cand[16];
#pragma unroll
    for (int c = 0; c < 16; ++c) {
        int j = lane + c * 64;
        float m2 = mi * sMask[j];
        float Dadj = Dv[c] + (1.0f - m2) * dmax;
        unsigned int bits = __float_as_uint(Dadj);
        cand[c] = fma((double)bits, 1024.0, (double)j);
    }

    const double KILL = 9.0e15;
    float myj = 0.0f;
    for (int r = 0; r < KNB; ++r) {
        // lane-local min: balanced fmin tree (v_min_f64)
        double a0 = fmin(cand[0], cand[1]);
        double a1 = fmin(cand[2], cand[3]);
        double a2 = fmin(cand[4], cand[5]);
        double a3 = fmin(cand[6], cand[7]);
        double a4 = fmin(cand[8], cand[9]);
        double a5 = fmin(cand[10], cand[11]);
        double a6 = fmin(cand[12], cand[13]);
        double a7 = fmin(cand[14], cand[15]);
        a0 = fmin(a0, a1); a2 = fmin(a2, a3); a4 = fmin(a4, a5); a6 = fmin(a6, a7);
        a0 = fmin(a0, a2); a4 = fmin(a4, a6);
        double m = fmin(a0, a4);
        // wave min
        for (int o = 32; o; o >>= 1) {
            double other = __shfl_down(m, o);
            m = fmin(m, other);
        }
        m = __shfl(m, 0);
        unsigned long long ku = (unsigned long long)m;   // exact
        int jw = __builtin_amdgcn_readfirstlane((int)(ku & 1023));
        bool own = (lane == (jw & 63));
        switch (jw >> 6) {   // scalar 16-way branch; one masked v_mov pair
            case 0:  if (own) cand[0]  = KILL; break;
            case 1:  if (own) cand[1]  = KILL; break;
            case 2:  if (own) cand[2]  = KILL; break;
            case 3:  if (own) cand[3]  = KILL; break;
            case 4:  if (own) cand[4]  = KILL; break;
            case 5:  if (own) cand[5]  = KILL; break;
            case 6:  if (own) cand[6]  = KILL; break;
            case 7:  if (own) cand[7]  = KILL; break;
            case 8:  if (own) cand[8]  = KILL; break;
            case 9:  if (own) cand[9]  = KILL; break;
            case 10: if (own) cand[10] = KILL; break;
            case 11: if (own) cand[11] = KILL; break;
            case 12: if (own) cand[12] = KILL; break;
            case 13: if (own) cand[13] = KILL; break;
            case 14: if (own) cand[14] = KILL; break;
            case 15: if (own) cand[15] = KILL; break;
        }
        if (lane == r) myj = (float)jw;
    }
    if (lane < KNB) out_idx[(size_t)row * KNB + lane] = myj;
}

// -------- Kernel 2: features -> FP8 MFMA GEMM -> LayerNorm, one block per (b,i) --------
// Proven best (r5, 236.9us total). r3 phase structure + FP8 e4m3 operands:
// mfma_f32_32x32x16_fp8_fp8 runs at f16 rate with HALF the bytes:
// fA 13.3KB (LDS 16.4KB total), ds_read_b64 A-frags, 8B/lane B loads,
// 4 cvt_pk_fp8 per chunk. absmax 0.252 vs threshold 20.48 (80x margin).
// Structural variants all tested and refuted: K-split (r4 +9.5us), B-reg hoist
// (r6 +13us), knn fusion (r8 +31us), 2-row blocks (r9 +5.5us).
__global__ __launch_bounds__(256) void edge_kernel(const float* __restrict__ X,
                                                   const int* __restrict__ ridx,
                                                   const float* __restrict__ W_pos,
                                                   const float* __restrict__ b_pos,
                                                   const unsigned char* __restrict__ WtF,
                                                   const float* __restrict__ gamma,
                                                   const float* __restrict__ beta,
                                                   const float* __restrict__ out_idx,
                                                   float* __restrict__ out_E) {
    int row = blockIdx.x;   // b*L + i
    int b = row >> 10;
    int i = row & 1023;
    int tid = threadIdx.x;

    // LDS overlay (16384 B):
    //  [0, 13312)      fA (A-fragments fp8) / atoms (31*15 f32, dead pre-build)
    //  [13312, 16312)  dist (30*25 f32)
    //  [0, 16384)      Esh (32x128 f32) after MFMA (fA + dist both dead)
    __shared__ __align__(16) char smem[16384];
    unsigned char* fA = (unsigned char*)smem;
    float* Esh = (float*)smem;
    float* atoms = (float*)smem;
    float* dist = (float*)(smem + 13312);

    // step 1: atoms for residue i and its 30 neighbors (out_idx is L2-hot).
    if (tid < 31) {
        int r = (tid == 0) ? i : (int)out_idx[(size_t)row * KNB + (tid - 1)];
        int base = (b * LL + r) * 12;
        float Nx = X[base + 0], Ny = X[base + 1], Nz = X[base + 2];
        float Cax = X[base + 3], Cay = X[base + 4], Caz = X[base + 5];
        float Cx = X[base + 6], Cy = X[base + 7], Cz = X[base + 8];
        float Ox = X[base + 9], Oy = X[base + 10], Oz = X[base + 11];
        float bx = Cax - Nx, by = Cay - Ny, bz = Caz - Nz;
        float cx = Cx - Cax, cy = Cy - Cay, cz = Cz - Caz;
        float ax = by * cz - bz * cy;
        float ay = bz * cx - bx * cz;
        float az = bx * cy - by * cx;
        float Cbx = -0.58273431f * ax + 0.56802827f * bx - 0.54067466f * cx + Cax;
        float Cby = -0.58273431f * ay + 0.56802827f * by - 0.54067466f * cy + Cay;
        float Cbz = -0.58273431f * az + 0.56802827f * bz - 0.54067466f * cz + Caz;
        float* A = &atoms[tid * 15];
        A[0] = Cax; A[1] = Cay; A[2] = Caz;
        A[3] = Nx;  A[4] = Ny;  A[5] = Nz;
        A[6] = Cx;  A[7] = Cy;  A[8] = Cz;
        A[9] = Ox;  A[10] = Oy; A[11] = Oz;
        A[12] = Cbx; A[13] = Cby; A[14] = Cbz;
    }
    __syncthreads();

    // step 2: 30*25 atom-pair distances (v_sqrt fine: feeds tolerance-checked RBF)
    for (int idx = tid; idx < KNB * 25; idx += 256) {
        int k = idx / 25;
        int p = idx - k * 25;
        const float* Ai = &atoms[PAIR_I_d[p] * 3];
        const float* Aj = &atoms[(1 + k) * 15 + PAIR_J_d[p] * 3];
        float dx = Ai[0] - Aj[0], dy = Ai[1] - Aj[1], dz = Ai[2] - Aj[2];
        dist[idx] = __builtin_amdgcn_sqrtf(dx * dx + dy * dy + dz * dz + 1e-6f);
    }
    __syncthreads();

    // step 3: build A-fragments (fp8) in MFMA order.
    // element (m,k): fA[((k>>4)*64 + m + 32*((k>>3)&1))*8 + (k&7)]  (bytes)
    // RBF via exact telescoping recurrence anchored at chunk CENTER (jj=4):
    //   f_4 = exp(2h*xc - h^2), b_4 = exp(-2h*xc - h^2), both decay by DK.
    // xc clamped to <=12 (NaN guard: fw=exp2(C1*xc-C0) would overflow past xc~42
    // while r4 flushed to 0 -> 0*inf; chunks with xc>7.3 are exactly 0 in fp8
    // either way, so the clamp is semantics-preserving).
    {
        int m = tid & 31;
        int kgb = tid >> 5;          // 0..7; kg parity == kgb parity
        float cbase = (kgb & 1) ? 14.4f : 5.8666668f;   // 1.6 + 4h (+ 8h odd chunks)
        const float SQL2E = 1.2011224f;   // sqrt(log2 e)
        const float C1 = 3.0777494f;      // 2h * log2 e
        const float C0 = 1.6414664f;      // h^2 * log2 e
        const float DK = 0.1027397f;      // exp(-2 h^2)
#pragma unroll
        for (int r = 0; r < 7; ++r) {
            int kg = kgb + 8 * r;
            if (kg < 52) {
                int lo, hi;
                if (m >= KNB) {
                    lo = 0; hi = 0;
                } else if (kg < 2) {
                    // positional features; dclip computed inline (L2-hot)
                    int jn = (int)out_idx[(size_t)row * KNB + m];
                    int off = ridx[row] - ridx[b * LL + jn] + MAXREL;
                    off = off < 0 ? 0 : (off > 2 * MAXREL ? 2 * MAXREL : off);
                    const float4* wp = (const float4*)&W_pos[off * NPOS + kg * 8];
                    const float4* bp = (const float4*)&b_pos[kg * 8];
                    float4 w0 = wp[0], w1 = wp[1];
                    float4 p0 = bp[0], p1 = bp[1];
                    lo = __builtin_amdgcn_cvt_pk_fp8_f32(w0.x + p0.x, w0.y + p0.y, 0, false);
                    lo = __builtin_amdgcn_cvt_pk_fp8_f32(w0.z + p0.z, w0.w + p0.w, lo, true);
                    hi = __builtin_amdgcn_cvt_pk_fp8_f32(w1.x + p1.x, w1.y + p1.y, 0, false);
                    hi = __builtin_amdgcn_cvt_pk_fp8_f32(w1.z + p1.z, w1.w + p1.w, hi, true);
                } else {
                    int p = (kg - 2) >> 1;               // atom-pair index
                    float d = dist[m * 25 + p];
                    float xc = fminf(fmaf(0.8f, d, -cbase), 12.0f);   // x at jj=4
                    float xs = xc * SQL2E;
                    float r4 = __builtin_amdgcn_exp2f(-xs * xs);
                    float fw = __builtin_amdgcn_exp2f(fmaf(C1, xc, -C0));
                    float bw = __builtin_amdgcn_exp2f(fmaf(-C1, xc, -C0));
                    float r5 = r4 * fw; fw *= DK;
                    float r6 = r5 * fw; fw *= DK;
                    float r7 = r6 * fw;
                    float r3 = r4 * bw; bw *= DK;
                    float r2 = r3 * bw; bw *= DK;
                    float r1 = r2 * bw; bw *= DK;
                    float r0 = r1 * bw;
                    lo = __builtin_amdgcn_cvt_pk_fp8_f32(r0, r1, 0, false);
                    lo = __builtin_amdgcn_cvt_pk_fp8_f32(r2, r3, lo, true);
                    hi = __builtin_amdgcn_cvt_pk_fp8_f32(r4, r5, 0, false);
                    hi = __builtin_amdgcn_cvt_pk_fp8_f32(r6, r7, hi, true);
                }
                int pos = ((kg >> 1) * 64 + m + 32 * (kg & 1)) * 8;
                long v = ((long)(unsigned int)hi << 32) | (unsigned int)lo;
                *(long*)(fA + pos) = v;
            }
        }
    }
    __syncthreads();

    // step 4: FP8 MFMA K-loop. wave wv computes 32 rows x cols [32wv, 32wv+32)
    int wv = tid >> 6;
    int l = tid & 63;
    floatx16 acc;
#pragma unroll
    for (int r = 0; r < 16; ++r) acc[r] = 0.0f;

    const long* Ap = (const long*)fA + l;                       // + kk*64
    const long* Bp = (const long*)WtF + wv * 64 + l;            // + kk*256
#pragma unroll 4
    for (int kk = 0; kk < NKK; ++kk) {
        long a = Ap[kk * 64];
        long bfr = Bp[kk * 256];
        acc = __builtin_amdgcn_mfma_f32_32x32x16_fp8_fp8(a, bfr, acc, 0, 0, 0);
    }
    __syncthreads();   // everyone done reading fA before overlay write

    // step 5: spill C to LDS (C layout: col=l&31, row=(r&3)+8*(r>>2)+4*(l>>5))
#pragma unroll
    for (int r = 0; r < 16; ++r) {
        int rr = (r & 3) + 8 * (r >> 2) + 4 * (l >> 5);
        Esh[rr * EDGE_C + wv * 32 + (l & 31)] = acc[r];
    }
    __syncthreads();

    // step 6: LayerNorm, one pass: sum + sumsq with interleaved butterflies,
    // var = E[x^2] - mean^2, v_rsq instead of IEEE 1/sqrt.
    int cg = tid & 31;
    int ky = tid >> 5;
    int c0 = cg * 4;
    float gam0 = gamma[c0 + 0], gam1 = gamma[c0 + 1];
    float gam2 = gamma[c0 + 2], gam3 = gamma[c0 + 3];
    float bet0 = beta[c0 + 0], bet1 = beta[c0 + 1];
    float bet2 = beta[c0 + 2], bet3 = beta[c0 + 3];

#pragma unroll
    for (int r2 = 0; r2 < 4; ++r2) {
        int e = ky + 8 * r2;
        float4 v = *(const float4*)&Esh[e * EDGE_C + c0];
        float s = (v.x + v.y) + (v.z + v.w);
        float q = fmaf(v.x, v.x, fmaf(v.y, v.y, fmaf(v.z, v.z, v.w * v.w)));
#pragma unroll
        for (int o = 16; o; o >>= 1) {
            s += __shfl_xor(s, o);    // two independent chains -> latency-hidden
            q += __shfl_xor(q, o);
        }
        float mean = s * 0.0078125f;
        float var = fmaf(-mean, mean, q * 0.0078125f);
        float inv = __builtin_amdgcn_rsqf(var + 1e-5f);
        if (e < KNB) {
            float ig0 = inv * gam0, ig1 = inv * gam1;
            float ig2 = inv * gam2, ig3 = inv * gam3;
            float4 o4;
            o4.x = fmaf(v.x, ig0, fmaf(-mean, ig0, bet0));
            o4.y = fmaf(v.y, ig1, fmaf(-mean, ig1, bet1));
            o4.z = fmaf(v.z, ig2, fmaf(-mean, ig2, bet2));
            o4.w = fmaf(v.w, ig3, fmaf(-mean, ig3, bet3));
            *(float4*)(out_E + ((size_t)(row * KNB + e)) * EDGE_C + c0) = o4;
        }
    }
}

extern "C" void kernel_launch(void* const* d_in, const int* in_sizes, int n_in,
                              void* d_out, int out_size, void* d_ws, size_t ws_size,
                              hipStream_t stream) {
    const float* X      = (const float*)d_in[0];
    const float* mask   = (const float*)d_in[1];
    const int*   ridx   = (const int*)d_in[2];
    const float* W_pos  = (const float*)d_in[6];
    const float* b_pos  = (const float*)d_in[7];
    const float* W_edge = (const float*)d_in[8];
    const float* gamma  = (const float*)d_in[9];
    const float* beta   = (const float*)d_in[10];

    float* out_E   = (float*)d_out;
    float* out_idx = out_E + (size_t)BB * LL * KNB * EDGE_C;   // E_idx stored as floats
    unsigned char* WtF = (unsigned char*)d_ws;                 // 53 KB fragment-linear fp8 W

    int knn_grid = 2048 + (WTF_N + 255) / 256;   // kNN blocks + folded W-prep blocks
    knn_kernel<<<knn_grid, 256, 0, stream>>>(X, mask, out_idx, W_edge, WtF);
    edge_kernel<<<BB * LL, 256, 0, stream>>>(X, ridx, W_pos, b_pos, WtF,
                                             gamma, beta, out_idx, out_E);
}